// Round 1
// 346.249 us; speedup vs baseline: 1.0243x; 1.0243x over previous
//
#include <hip/hip_runtime.h>

constexpr int B  = 2;
constexpr int NH = 8;
constexpr int L  = 512;
constexpr int D  = 64;
constexpr float INV_TEMP = 0.125f;   // 1/sqrt(D) = 1/8

// ---------------------------------------------------------------------------
// K1: S1[b,h,i,j] = (q[b,h,i,:]/8) . k[b,h,j,:]  -> d_ws   (unchanged)
// grid (16, L/64, L/128), block 256. Tiles: 64 i x 128 j, K=64 staged once.
// ---------------------------------------------------------------------------
__global__ __launch_bounds__(256) void k1_qk(const float* __restrict__ q,
                                             const float* __restrict__ k,
                                             float* __restrict__ s1) {
  const int bh = blockIdx.x, it = blockIdx.y, jt = blockIdx.z;
  __shared__ float Qs[64][68];    // [i][d], stride 68: b128-aligned, 2-way banks
  __shared__ float Ks[128][68];   // [j][d]
  const int t = threadIdx.x;
  const float* qb = q + ((size_t)bh * L + it * 64) * D;
  const float* kb = k + ((size_t)bh * L + jt * 128) * D;
#pragma unroll
  for (int n0 = 0; n0 < 4; ++n0) {            // Q tile: 64x64 = 1024 float4
    int n = t + (n0 << 8);
    int r = n >> 4, c = (n & 15) << 2;
    float4 a = *(const float4*)(qb + (size_t)r * D + c);
    a.x *= INV_TEMP; a.y *= INV_TEMP; a.z *= INV_TEMP; a.w *= INV_TEMP;
    *(float4*)&Qs[r][c] = a;
  }
#pragma unroll
  for (int n0 = 0; n0 < 8; ++n0) {            // K tile: 128x64 = 2048 float4
    int n = t + (n0 << 8);
    int r = n >> 4, c = (n & 15) << 2;
    *(float4*)&Ks[r][c] = *(const float4*)(kb + (size_t)r * D + c);
  }
  __syncthreads();
  const int i0 = t >> 4, j0 = t & 15;         // i = i0+16m (m<4), j = j0+16n (n<8)
  float acc[4][8] = {};
#pragma unroll 1
  for (int kc = 0; kc < 64; kc += 4) {
    float4 a[4], b[8];
#pragma unroll
    for (int m = 0; m < 4; ++m) a[m] = *(const float4*)&Qs[i0 + 16 * m][kc];
#pragma unroll
    for (int n = 0; n < 8; ++n) b[n] = *(const float4*)&Ks[j0 + 16 * n][kc];
#pragma unroll
    for (int m = 0; m < 4; ++m)
#pragma unroll
      for (int n = 0; n < 8; ++n)
        acc[m][n] = fmaf(a[m].x, b[n].x,
                    fmaf(a[m].y, b[n].y,
                    fmaf(a[m].z, b[n].z,
                    fmaf(a[m].w, b[n].w, acc[m][n]))));
  }
  float* sb = s1 + ((size_t)bh * L + it * 64) * L + jt * 128;
#pragma unroll
  for (int m = 0; m < 4; ++m) {
    float* srow = sb + (size_t)(i0 + 16 * m) * L;
#pragma unroll
    for (int n = 0; n < 8; ++n) srow[j0 + 16 * n] = acc[m][n];
  }
}

// ---------------------------------------------------------------------------
// K2 v2: one block per (b,i), 512 threads (8 waves -> 32 waves/CU = 100% occ
// ceiling; was 256 threads -> 16 waves/CU max = the 37% occupancy cap).
//  A: wave w = head w. adj_k staged in 64-row chunks with REGISTER PREFETCH
//     (issue next chunk's loads before computing current -> HBM latency hidden
//     across the barrier; ~16 KB in flight per block, 64 KB per CU > BDP).
//  B: softmax, one head per 64-lane wave.
//  C: wave w owns j-slice [64w,64w+64) and computes ALL 8 heads for it:
//     adj_v row read exactly once per block (was 4x), v rows once each.
//     Two 4-head groups keep live VGPRs ~50. Partials combined via LDS
//     (reusing the ak buffer), then one coalesced out-row per wave.
// ---------------------------------------------------------------------------
__global__ __launch_bounds__(512, 8) void k2_fused(
    const float* __restrict__ q, const float* __restrict__ v,
    const float* __restrict__ adj_k, const float* __restrict__ adj_v,
    const int* __restrict__ mask, const float* __restrict__ s1,
    float* __restrict__ out, float* __restrict__ attn) {
  const int b = blockIdx.x >> 9, i = blockIdx.x & (L - 1);
  const int t = threadIdx.x;
  const int lane = t & 63;
  const int w = __builtin_amdgcn_readfirstlane(t >> 6);   // wave id 0..7

  __shared__ float sc[NH][L];      // 16 KB: scores, then probs
  __shared__ float ak[64][65];     // 16.6 KB: adj_k chunk; reused as opart in C
  // total 33 KB -> 4 blocks/CU by LDS; __launch_bounds__(512,8) caps VGPR<=64

  // ---------------- phase A: sc[h][j] = s1 + (q[h].adj_k[j])/8 -------------
  const float* akb = adj_k + ((size_t)b * L + i) * (size_t)(L * D);
  const float* qh  = q  + (((size_t)b * NH + w) * L + i) * D;   // wave-uniform
  const float* s1r = s1 + (((size_t)b * NH + w) * L + i) * L;

  const int sr0 = t >> 4, scol = (t & 15) << 2, sr1 = sr0 + 32;
  float4 pf0 = *(const float4*)(akb + (size_t)sr0 * D + scol);  // chunk 0
  float4 pf1 = *(const float4*)(akb + (size_t)sr1 * D + scol);

  for (int jc = 0; jc < L; jc += 64) {
    // write-late: previous chunk's readers finished at trailing sync
    ak[sr0][scol] = pf0.x; ak[sr0][scol + 1] = pf0.y;
    ak[sr0][scol + 2] = pf0.z; ak[sr0][scol + 3] = pf0.w;
    ak[sr1][scol] = pf1.x; ak[sr1][scol + 1] = pf1.y;
    ak[sr1][scol + 2] = pf1.z; ak[sr1][scol + 3] = pf1.w;
    __syncthreads();
    if (jc + 64 < L) {                        // issue-early: next chunk in flight
      const float* nb = akb + (size_t)(jc + 64) * D;
      pf0 = *(const float4*)(nb + (size_t)sr0 * D + scol);
      pf1 = *(const float4*)(nb + (size_t)sr1 * D + scol);
    }
    float acc = 0.f;                          // this thread: j = jc+lane
#pragma unroll
    for (int dc = 0; dc < D; dc += 4) {
      float4 q4 = *(const float4*)(qh + dc);  // scalar path (uniform addr)
      acc = fmaf(q4.x, ak[lane][dc],
            fmaf(q4.y, ak[lane][dc + 1],
            fmaf(q4.z, ak[lane][dc + 2],
            fmaf(q4.w, ak[lane][dc + 3], acc))));
    }
    sc[w][jc + lane] = s1r[jc + lane] + acc * INV_TEMP;
    __syncthreads();
  }

  // ---------------- phase B: mask + softmax, head w per wave ---------------
  {
    const int* mrow = mask + b * L;
    float* arow = attn + (((size_t)b * NH + w) * L + i) * L;
    float vals[8];
    float mx = -3.4e38f;
#pragma unroll
    for (int m = 0; m < 8; ++m) {
      int jj = lane + (m << 6);
      float s = sc[w][jj];
      s = (mrow[jj] == 0) ? -10000.0f : s;
      vals[m] = s;
      mx = fmaxf(mx, s);
    }
#pragma unroll
    for (int off = 32; off > 0; off >>= 1) mx = fmaxf(mx, __shfl_xor(mx, off, 64));
    float sum = 0.f;
#pragma unroll
    for (int m = 0; m < 8; ++m) { vals[m] = __expf(vals[m] - mx); sum += vals[m]; }
#pragma unroll
    for (int off = 32; off > 0; off >>= 1) sum += __shfl_xor(sum, off, 64);
    const float inv = 1.0f / sum;
#pragma unroll
    for (int m = 0; m < 8; ++m) {
      int jj = lane + (m << 6);
      float p = vals[m] * inv;
      arow[jj] = p;       // attn output (coalesced 256B per store)
      sc[w][jj] = p;      // reuse for phase C
    }
  }
  __syncthreads();        // all probs visible; ak free for reuse

  // ---------------- phase C: out[h][d] = sum_j p[h][j]*(adj_v[j]+v[h][j]) --
  {
    const int jb = w << 6;                    // this wave's j-slice
    const float* avp = adj_v + ((size_t)b * L + i) * (size_t)(L * D)
                             + (size_t)jb * D + lane;              // lane = d
    const float* vb  = v + (size_t)b * NH * (size_t)(L * D)
                         + (size_t)jb * D + lane;
    float* opart = &ak[0][0];                 // [wave][head][d] partials
#pragma unroll
    for (int g = 0; g < 2; ++g) {             // 4 heads per group: ~50 VGPR live
      const int h0 = g * 4;
      float p0 = sc[h0][jb + lane],     p1 = sc[h0 + 1][jb + lane],
            p2 = sc[h0 + 2][jb + lane], p3 = sc[h0 + 3][jb + lane];
      const float* w0 = vb + (size_t)(h0    ) * (L * D);
      const float* w1 = vb + (size_t)(h0 + 1) * (L * D);
      const float* w2 = vb + (size_t)(h0 + 2) * (L * D);
      const float* w3 = vb + (size_t)(h0 + 3) * (L * D);
      float o0 = 0.f, o1 = 0.f, o2 = 0.f, o3 = 0.f;
#pragma unroll 4
      for (int j = 0; j < 64; ++j) {          // j uniform -> v_readlane
        float av = avp[(size_t)j * D];        // adj_v row: read ONCE per block
        float x0 = w0[(size_t)j * D];
        float x1 = w1[(size_t)j * D];
        float x2 = w2[(size_t)j * D];
        float x3 = w3[(size_t)j * D];
        float pj0 = __uint_as_float(__builtin_amdgcn_readlane(__float_as_uint(p0), j));
        float pj1 = __uint_as_float(__builtin_amdgcn_readlane(__float_as_uint(p1), j));
        float pj2 = __uint_as_float(__builtin_amdgcn_readlane(__float_as_uint(p2), j));
        float pj3 = __uint_as_float(__builtin_amdgcn_readlane(__float_as_uint(p3), j));
        o0 = fmaf(pj0, av + x0, o0);
        o1 = fmaf(pj1, av + x1, o1);
        o2 = fmaf(pj2, av + x2, o2);
        o3 = fmaf(pj3, av + x3, o3);
      }
      opart[(w << 9) + (h0    ) * 64 + lane] = o0;
      opart[(w << 9) + (h0 + 1) * 64 + lane] = o1;
      opart[(w << 9) + (h0 + 2) * 64 + lane] = o2;
      opart[(w << 9) + (h0 + 3) * 64 + lane] = o3;
    }
    __syncthreads();
    float r = 0.f;                            // wave w reduces head w
#pragma unroll
    for (int wv = 0; wv < 8; ++wv) r += opart[(wv << 9) + (w << 6) + lane];
    out[(((size_t)b * NH + w) * L + i) * D + lane] = r;
  }
}

// ---------------------------------------------------------------------------
extern "C" void kernel_launch(void* const* d_in, const int* in_sizes, int n_in,
                              void* d_out, int out_size, void* d_ws, size_t ws_size,
                              hipStream_t stream) {
  const float* q     = (const float*)d_in[0];
  const float* k     = (const float*)d_in[1];
  const float* v     = (const float*)d_in[2];
  const float* adj_k = (const float*)d_in[3];
  const float* adj_v = (const float*)d_in[4];
  const int*   mask  = (const int*)d_in[5];
  float* out  = (float*)d_out;
  float* attn = out + (size_t)B * NH * L * D;   // second output region
  float* s1   = (float*)d_ws;                   // B*NH*L*L fp32 = 16.8 MB

  dim3 g1(B * NH, L / 64, L / 128);
  k1_qk<<<g1, 256, 0, stream>>>(q, k, s1);
  k2_fused<<<B * L, 512, 0, stream>>>(q, v, adj_k, adj_v, mask, s1, out, attn);
}

// Round 3
// 332.719 us; speedup vs baseline: 1.0660x; 1.0407x over previous
//
#include <hip/hip_runtime.h>

constexpr int B  = 2;
constexpr int NH = 8;
constexpr int L  = 512;
constexpr int D  = 64;
constexpr float INV_TEMP = 0.125f;   // 1/sqrt(D) = 1/8

// ---------------------------------------------------------------------------
// K1: S1[b,h,i,j] = (q[b,h,i,:]/8) . k[b,h,j,:]  -> d_ws
// grid (16, 8, 8) = 1024 blocks. Tiles 64i x 64j, K=64 staged once.
// ---------------------------------------------------------------------------
__global__ __launch_bounds__(256) void k1_qk(const float* __restrict__ q,
                                             const float* __restrict__ k,
                                             float* __restrict__ s1) {
  const int bh = blockIdx.x, it = blockIdx.y, jt = blockIdx.z;
  __shared__ float Qs[64][68];    // stride 68: b128-aligned, 2-way banks (free)
  __shared__ float Ks[64][68];
  const int t = threadIdx.x;
  const float* qb = q + ((size_t)bh * L + it * 64) * D;
  const float* kb = k + ((size_t)bh * L + jt * 64) * D;
#pragma unroll
  for (int n0 = 0; n0 < 4; ++n0) {            // 64x64 = 1024 float4 each
    int n = t + (n0 << 8);
    int r = n >> 4, c = (n & 15) << 2;
    float4 a = *(const float4*)(qb + (size_t)r * D + c);
    a.x *= INV_TEMP; a.y *= INV_TEMP; a.z *= INV_TEMP; a.w *= INV_TEMP;
    *(float4*)&Qs[r][c] = a;
    *(float4*)&Ks[r][c] = *(const float4*)(kb + (size_t)r * D + c);
  }
  __syncthreads();
  const int i0 = t >> 4, j0 = t & 15;         // i = i0+16m, j = j0+16n
  float acc[4][4] = {};
#pragma unroll 1
  for (int kc = 0; kc < 64; kc += 4) {
    float4 a[4], b[4];
#pragma unroll
    for (int m = 0; m < 4; ++m) a[m] = *(const float4*)&Qs[i0 + 16 * m][kc];
#pragma unroll
    for (int n = 0; n < 4; ++n) b[n] = *(const float4*)&Ks[j0 + 16 * n][kc];
#pragma unroll
    for (int m = 0; m < 4; ++m)
#pragma unroll
      for (int n = 0; n < 4; ++n)
        acc[m][n] = fmaf(a[m].x, b[n].x,
                    fmaf(a[m].y, b[n].y,
                    fmaf(a[m].z, b[n].z,
                    fmaf(a[m].w, b[n].w, acc[m][n]))));
  }
  float* sb = s1 + ((size_t)bh * L + it * 64) * L + jt * 64;
#pragma unroll
  for (int m = 0; m < 4; ++m) {
    float* srow = sb + (size_t)(i0 + 16 * m) * L;
#pragma unroll
    for (int n = 0; n < 4; ++n) srow[j0 + 16 * n] = acc[m][n];
  }
}

// ---------------------------------------------------------------------------
// K2 v4: one block per (b,i), 512 threads, launch_bounds(512,4).
//  A: NO LDS staging. Lane j gathers its whole adj_k row into 16 float4 regs
//     and dots against all 8 q heads (q rows wave-uniform -> s_load).
//  B: softmax, head w per wave.
//  C: adj_v term only. Wave w covers j-slice [64w,64w+64); per-wave partials
//     are COMBINED ACROSS WAVES via LDS (v3 bug: waves overwrote each other's
//     out[h][d] with 1/8-partials -> absmax 1.55). sc is dead after the last
//     prob read, so it is reused as the partial buffer behind a barrier.
// ---------------------------------------------------------------------------
__global__ __launch_bounds__(512, 4) void k2_fused(
    const float* __restrict__ q, const float* __restrict__ adj_k,
    const float* __restrict__ adj_v, const int* __restrict__ mask,
    const float* __restrict__ s1, float* __restrict__ out,
    float* __restrict__ attn) {
  const int b = blockIdx.x >> 9, i = blockIdx.x & (L - 1);
  const int t = threadIdx.x;
  const int lane = t & 63;
  const int w = __builtin_amdgcn_readfirstlane(t >> 6);   // wave id 0..7
  const int jb = w << 6;                                  // wave's j-slice
  __shared__ float sc[NH][L];      // 16 KB: scores -> probs -> out-partials

  // ---------------- phase A: sc[h][j] = s1 + (q[h].adj_k[j])/8, masked -----
  {
    const float* akr = adj_k + (((size_t)b * L + i) * L + jb + lane) * D;
    float4 row[16];                            // whole row in regs (64 VGPR)
#pragma unroll
    for (int dc = 0; dc < 16; ++dc) row[dc] = *(const float4*)(akr + 4 * dc);
    const int mv = mask[b * L + jb + lane];
    float acc[NH];
#pragma unroll
    for (int h = 0; h < NH; ++h) {
      const float* qh = q + (((size_t)b * NH + h) * L + i) * D;  // uniform
      float a0 = 0.f, a1 = 0.f;                // 2 chains per head
#pragma unroll
      for (int dc = 0; dc < 16; dc += 2) {
        float4 q4 = *(const float4*)(qh + 4 * dc);
        float4 q5 = *(const float4*)(qh + 4 * dc + 4);
        a0 = fmaf(q4.x, row[dc].x, fmaf(q4.y, row[dc].y,
             fmaf(q4.z, row[dc].z, fmaf(q4.w, row[dc].w, a0))));
        a1 = fmaf(q5.x, row[dc + 1].x, fmaf(q5.y, row[dc + 1].y,
             fmaf(q5.z, row[dc + 1].z, fmaf(q5.w, row[dc + 1].w, a1))));
      }
      acc[h] = a0 + a1;
    }
#pragma unroll
    for (int h = 0; h < NH; ++h) {
      float s = s1[(((size_t)b * NH + h) * L + i) * L + jb + lane]
                + acc[h] * INV_TEMP;
      sc[h][jb + lane] = (mv == 0) ? -10000.0f : s;
    }
  }
  __syncthreads();

  // ---------------- phase B: softmax, head w per wave ----------------------
  {
    float* arow = attn + (((size_t)b * NH + w) * L + i) * L;
    float vals[8];
    float mx = -3.4e38f;
#pragma unroll
    for (int m = 0; m < 8; ++m) {
      float s = sc[w][lane + (m << 6)];
      vals[m] = s;
      mx = fmaxf(mx, s);
    }
#pragma unroll
    for (int off = 32; off > 0; off >>= 1) mx = fmaxf(mx, __shfl_xor(mx, off, 64));
    float sum = 0.f;
#pragma unroll
    for (int m = 0; m < 8; ++m) { vals[m] = __expf(vals[m] - mx); sum += vals[m]; }
#pragma unroll
    for (int off = 32; off > 0; off >>= 1) sum += __shfl_xor(sum, off, 64);
    const float inv = 1.0f / sum;
#pragma unroll
    for (int m = 0; m < 8; ++m) {
      int jj = lane + (m << 6);
      float p = vals[m] * inv;
      arow[jj] = p;       // attn output (coalesced 256B stores)
      sc[w][jj] = p;      // reuse for phase C
    }
  }
  __syncthreads();

  // ---------------- phase C: out[h][d] = sum_j p[h][j]*adj_v[j][d] ---------
  {
    const int js = lane >> 4, dq = lane & 15;  // 4 j's per step, d = 4*dq
    const float* avb = adj_v + ((size_t)b * L + i) * (size_t)(L * D)
                             + (size_t)jb * D + 4 * dq;
    float4 o[NH];
#pragma unroll
    for (int h = 0; h < NH; ++h) o[h] = make_float4(0.f, 0.f, 0.f, 0.f);
#pragma unroll 4
    for (int jj = 0; jj < 64; jj += 4) {       // coalesced 1KB f4 loads
      const float4 av = *(const float4*)(avb + (size_t)(jj + js) * D);
      const int j = jb + jj + js;
#pragma unroll
      for (int h = 0; h < NH; ++h) {
        float p = sc[h][j];                    // 4 distinct banks, broadcast
        o[h].x = fmaf(p, av.x, o[h].x);
        o[h].y = fmaf(p, av.y, o[h].y);
        o[h].z = fmaf(p, av.z, o[h].z);
        o[h].w = fmaf(p, av.w, o[h].w);
      }
    }
#pragma unroll
    for (int h = 0; h < NH; ++h) {             // reduce over js (xor 16,32)
      o[h].x += __shfl_xor(o[h].x, 16, 64); o[h].x += __shfl_xor(o[h].x, 32, 64);
      o[h].y += __shfl_xor(o[h].y, 16, 64); o[h].y += __shfl_xor(o[h].y, 32, 64);
      o[h].z += __shfl_xor(o[h].z, 16, 64); o[h].z += __shfl_xor(o[h].z, 32, 64);
      o[h].w += __shfl_xor(o[h].w, 16, 64); o[h].w += __shfl_xor(o[h].w, 32, 64);
    }
    // ---- cross-wave combine (the v3 fix) ----
    __syncthreads();                           // all waves done reading probs
    float* opart = &sc[0][0];                  // [wave][head][64d] = 16 KB
    if (js == 0) {
#pragma unroll
      for (int h = 0; h < NH; ++h)
        *(float4*)(opart + (((w << 3) + h) << 6) + 4 * dq) = o[h];
    }
    __syncthreads();
    float r = 0.f;                             // wave w reduces head w, lane=d
#pragma unroll
    for (int wv = 0; wv < 8; ++wv) r += opart[(((wv << 3) + w) << 6) + lane];
    out[(((size_t)b * NH + w) * L + i) * D + lane] = r;
  }
}

// ---------------------------------------------------------------------------
// K3: out[b,h,i,d] += sum_j attn[b,h,i,j] * v[b,h,j,d]   (tiled GEMM)
// grid (16, 16): i-tile 32, d=64, j staged 64 at a time. v gets full LDS
// reuse here. Runs after k2 on same stream (reads out, adds, stores).
// ---------------------------------------------------------------------------
__global__ __launch_bounds__(256) void k3_av(const float* __restrict__ attn,
                                             const float* __restrict__ v,
                                             float* __restrict__ out) {
  const int bh = blockIdx.x, it = blockIdx.y;
  __shared__ float As[32][68];    // attn tile [i][j], b128-aligned reads
  __shared__ float Vt[64][65];    // v tile transposed [d][j], stride 65
  const int t = threadIdx.x;
  const float* ab = attn + ((size_t)bh * L + it * 32) * L;
  const float* vb = v + (size_t)bh * (size_t)(L * D);
  const int i0 = t >> 4, j0 = t & 15;         // i = i0+16m (m<2), d = j0+16n
  float acc[2][4] = {};
#pragma unroll 1
  for (int jc = 0; jc < L; jc += 64) {
    __syncthreads();
#pragma unroll
    for (int n0 = 0; n0 < 2; ++n0) {          // attn: 32x64 = 512 f4
      int n = t + (n0 << 8);
      int r = n >> 4, c = (n & 15) << 2;
      *(float4*)&As[r][c] = *(const float4*)(ab + (size_t)r * L + jc + c);
    }
#pragma unroll
    for (int n0 = 0; n0 < 4; ++n0) {          // v: 64x64 = 1024 f4, transpose
      int n = t + (n0 << 8);
      int r = n >> 4, c = (n & 15) << 2;
      float4 a = *(const float4*)(vb + (size_t)(jc + r) * D + c);
      Vt[c][r] = a.x; Vt[c + 1][r] = a.y; Vt[c + 2][r] = a.z; Vt[c + 3][r] = a.w;
    }
    __syncthreads();
#pragma unroll 1
    for (int kc = 0; kc < 64; kc += 4) {
      float4 a[2];
#pragma unroll
      for (int m = 0; m < 2; ++m) a[m] = *(const float4*)&As[i0 + 16 * m][kc];
      float bb[4][4];
#pragma unroll
      for (int n = 0; n < 4; ++n) {
        const float* vr = &Vt[j0 + 16 * n][kc];
        bb[n][0] = vr[0]; bb[n][1] = vr[1]; bb[n][2] = vr[2]; bb[n][3] = vr[3];
      }
#pragma unroll
      for (int m = 0; m < 2; ++m)
#pragma unroll
        for (int n = 0; n < 4; ++n)
          acc[m][n] = fmaf(a[m].x, bb[n][0],
                      fmaf(a[m].y, bb[n][1],
                      fmaf(a[m].z, bb[n][2],
                      fmaf(a[m].w, bb[n][3], acc[m][n]))));
    }
  }
  float* ob = out + ((size_t)bh * L + it * 32) * D;
#pragma unroll
  for (int m = 0; m < 2; ++m)
#pragma unroll
    for (int n = 0; n < 4; ++n) {
      float* p = ob + (size_t)(i0 + 16 * m) * D + j0 + 16 * n;
      *p += acc[m][n];                        // RMW; k2 ran first (same stream)
    }
}

// ---------------------------------------------------------------------------
extern "C" void kernel_launch(void* const* d_in, const int* in_sizes, int n_in,
                              void* d_out, int out_size, void* d_ws, size_t ws_size,
                              hipStream_t stream) {
  const float* q     = (const float*)d_in[0];
  const float* k     = (const float*)d_in[1];
  const float* v     = (const float*)d_in[2];
  const float* adj_k = (const float*)d_in[3];
  const float* adj_v = (const float*)d_in[4];
  const int*   mask  = (const int*)d_in[5];
  float* out  = (float*)d_out;
  float* attn = out + (size_t)B * NH * L * D;   // second output region
  float* s1   = (float*)d_ws;                   // B*NH*L*L fp32 = 16.8 MB

  dim3 g1(B * NH, L / 64, L / 64);
  k1_qk<<<g1, 256, 0, stream>>>(q, k, s1);
  k2_fused<<<B * L, 512, 0, stream>>>(q, adj_k, adj_v, mask, s1, out, attn);
  dim3 g3(B * NH, L / 32);
  k3_av<<<g3, 256, 0, stream>>>(attn, v, out);
}

// Round 4
// 326.098 us; speedup vs baseline: 1.0876x; 1.0203x over previous
//
#include <hip/hip_runtime.h>

constexpr int B  = 2;
constexpr int NH = 8;
constexpr int L  = 512;
constexpr int D  = 64;
constexpr float INV_TEMP = 0.125f;   // 1/sqrt(D) = 1/8

// ---------------------------------------------------------------------------
// K1: S1[b,h,i,j] = (q[b,h,i,:]/8) . k[b,h,j,:]  -> d_ws
// grid (16, 8, 8) = 1024 blocks. Tiles 64i x 64j, K=64 staged once.
// ---------------------------------------------------------------------------
__global__ __launch_bounds__(256) void k1_qk(const float* __restrict__ q,
                                             const float* __restrict__ k,
                                             float* __restrict__ s1) {
  const int bh = blockIdx.x, it = blockIdx.y, jt = blockIdx.z;
  __shared__ float Qs[64][68];    // stride 68: b128-aligned, 2-way banks (free)
  __shared__ float Ks[64][68];
  const int t = threadIdx.x;
  const float* qb = q + ((size_t)bh * L + it * 64) * D;
  const float* kb = k + ((size_t)bh * L + jt * 64) * D;
#pragma unroll
  for (int n0 = 0; n0 < 4; ++n0) {            // 64x64 = 1024 float4 each
    int n = t + (n0 << 8);
    int r = n >> 4, c = (n & 15) << 2;
    float4 a = *(const float4*)(qb + (size_t)r * D + c);
    a.x *= INV_TEMP; a.y *= INV_TEMP; a.z *= INV_TEMP; a.w *= INV_TEMP;
    *(float4*)&Qs[r][c] = a;
    *(float4*)&Ks[r][c] = *(const float4*)(kb + (size_t)r * D + c);
  }
  __syncthreads();
  const int i0 = t >> 4, j0 = t & 15;         // i = i0+16m, j = j0+16n
  float acc[4][4] = {};
#pragma unroll 1
  for (int kc = 0; kc < 64; kc += 4) {
    float4 a[4], b[4];
#pragma unroll
    for (int m = 0; m < 4; ++m) a[m] = *(const float4*)&Qs[i0 + 16 * m][kc];
#pragma unroll
    for (int n = 0; n < 4; ++n) b[n] = *(const float4*)&Ks[j0 + 16 * n][kc];
#pragma unroll
    for (int m = 0; m < 4; ++m)
#pragma unroll
      for (int n = 0; n < 4; ++n)
        acc[m][n] = fmaf(a[m].x, b[n].x,
                    fmaf(a[m].y, b[n].y,
                    fmaf(a[m].z, b[n].z,
                    fmaf(a[m].w, b[n].w, acc[m][n]))));
  }
  float* sb = s1 + ((size_t)bh * L + it * 64) * L + jt * 64;
#pragma unroll
  for (int m = 0; m < 4; ++m) {
    float* srow = sb + (size_t)(i0 + 16 * m) * L;
#pragma unroll
    for (int n = 0; n < 4; ++n) srow[j0 + 16 * n] = acc[m][n];
  }
}

// ---------------------------------------------------------------------------
// K2 v5: one block per (b,i), 512 threads, launch_bounds(512,4).
//  A: adj_k staged in 64-row LDS chunks via COALESCED loads (v4's per-lane-row
//     global gather was 64-way address-divergent: 64 cache lines/instr ->
//     TA-issue-limited at 1.8 TB/s). T14: prefetch chunk c+1 (+s1,+mask) into
//     regs, sched_barrier(0) pins the issue before compute. Wave w = head w;
//     lane j reads its row as b128 stride-68 (bank floor, no excess conflict).
//  B: softmax, head w per wave (unchanged, passed).
//  C: adj_v term, 16-lane-coalesced streams, shfl-reduce, cross-wave combine
//     via LDS (unchanged, passed). unroll 4 -> 8 for more loads in flight.
// ---------------------------------------------------------------------------
__global__ __launch_bounds__(512, 4) void k2_fused(
    const float* __restrict__ q, const float* __restrict__ adj_k,
    const float* __restrict__ adj_v, const int* __restrict__ mask,
    const float* __restrict__ s1, float* __restrict__ out,
    float* __restrict__ attn) {
  const int b = blockIdx.x >> 9, i = blockIdx.x & (L - 1);
  const int t = threadIdx.x;
  const int lane = t & 63;
  const int w = __builtin_amdgcn_readfirstlane(t >> 6);   // wave id 0..7
  __shared__ float sc[NH][L];      // 16 KB: scores -> probs -> out-partials
  __shared__ float ak[64][68];     // 17 KB: adj_k chunk (stride 68: b128 floor)

  // ---------------- phase A: sc[h][j] = s1 + (q[h].adj_k[j])/8, masked -----
  {
    const float* akb = adj_k + ((size_t)b * L + i) * (size_t)(L * D);
    const float* qh  = q  + (((size_t)b * NH + w) * L + i) * D;  // uniform
    const float* s1r = s1 + (((size_t)b * NH + w) * L + i) * L;
    const int*   mr  = mask + b * L;

    // staging layout: 512 threads x 2 float4 = 64 rows x 64 cols, coalesced
    const int sr0 = t >> 4, scol = (t & 15) << 2, sr1 = sr0 + 32;
    float4 pf0 = *(const float4*)(akb + (size_t)sr0 * D + scol);
    float4 pf1 = *(const float4*)(akb + (size_t)sr1 * D + scol);
    float s1pf = s1r[lane];                   // chunk 0 scores row
    int   mpf  = mr[lane];

    for (int jc = 0; jc < L; jc += 64) {
      // write-late: previous chunk's readers finished at trailing sync
      *(float4*)&ak[sr0][scol] = pf0;
      *(float4*)&ak[sr1][scol] = pf1;
      __syncthreads();
      float s1v = s1pf;
      int   mv  = mpf;
      if (jc + 64 < L) {                      // issue-early: next chunk
        const float* nb = akb + (size_t)(jc + 64) * D;
        pf0  = *(const float4*)(nb + (size_t)sr0 * D + scol);
        pf1  = *(const float4*)(nb + (size_t)sr1 * D + scol);
        s1pf = s1r[jc + 64 + lane];
        mpf  = mr[jc + 64 + lane];
      }
      __builtin_amdgcn_sched_barrier(0);      // pin: prefetch issued first
      float acc0 = 0.f, acc1 = 0.f;           // lane j = jc+lane, head w
#pragma unroll
      for (int dc = 0; dc < D; dc += 8) {
        float4 a0 = *(const float4*)&ak[lane][dc];
        float4 a1 = *(const float4*)&ak[lane][dc + 4];
        float4 q0 = *(const float4*)(qh + dc);       // s_load (uniform)
        float4 q1 = *(const float4*)(qh + dc + 4);
        acc0 = fmaf(q0.x, a0.x, fmaf(q0.y, a0.y,
               fmaf(q0.z, a0.z, fmaf(q0.w, a0.w, acc0))));
        acc1 = fmaf(q1.x, a1.x, fmaf(q1.y, a1.y,
               fmaf(q1.z, a1.z, fmaf(q1.w, a1.w, acc1))));
      }
      float s = s1v + (acc0 + acc1) * INV_TEMP;
      sc[w][jc + lane] = (mv == 0) ? -10000.0f : s;
      __syncthreads();
    }
  }

  // ---------------- phase B: softmax, head w per wave ----------------------
  {
    float* arow = attn + (((size_t)b * NH + w) * L + i) * L;
    float vals[8];
    float mx = -3.4e38f;
#pragma unroll
    for (int m = 0; m < 8; ++m) {
      float s = sc[w][lane + (m << 6)];
      vals[m] = s;
      mx = fmaxf(mx, s);
    }
#pragma unroll
    for (int off = 32; off > 0; off >>= 1) mx = fmaxf(mx, __shfl_xor(mx, off, 64));
    float sum = 0.f;
#pragma unroll
    for (int m = 0; m < 8; ++m) { vals[m] = __expf(vals[m] - mx); sum += vals[m]; }
#pragma unroll
    for (int off = 32; off > 0; off >>= 1) sum += __shfl_xor(sum, off, 64);
    const float inv = 1.0f / sum;
#pragma unroll
    for (int m = 0; m < 8; ++m) {
      int jj = lane + (m << 6);
      float p = vals[m] * inv;
      arow[jj] = p;       // attn output (coalesced 256B stores)
      sc[w][jj] = p;      // reuse for phase C
    }
  }
  __syncthreads();

  // ---------------- phase C: out[h][d] = sum_j p[h][j]*adj_v[j][d] ---------
  {
    const int jb = w << 6;                     // wave's j-slice
    const int js = lane >> 4, dq = lane & 15;  // 4 j's per step, d = 4*dq
    const float* avb = adj_v + ((size_t)b * L + i) * (size_t)(L * D)
                             + (size_t)jb * D + 4 * dq;
    float4 o[NH];
#pragma unroll
    for (int h = 0; h < NH; ++h) o[h] = make_float4(0.f, 0.f, 0.f, 0.f);
#pragma unroll 8
    for (int jj = 0; jj < 64; jj += 4) {       // coalesced 1KB f4 loads
      const float4 av = *(const float4*)(avb + (size_t)(jj + js) * D);
      const int j = jb + jj + js;
#pragma unroll
      for (int h = 0; h < NH; ++h) {
        float p = sc[h][j];                    // 4 distinct banks, broadcast
        o[h].x = fmaf(p, av.x, o[h].x);
        o[h].y = fmaf(p, av.y, o[h].y);
        o[h].z = fmaf(p, av.z, o[h].z);
        o[h].w = fmaf(p, av.w, o[h].w);
      }
    }
#pragma unroll
    for (int h = 0; h < NH; ++h) {             // reduce over js (xor 16,32)
      o[h].x += __shfl_xor(o[h].x, 16, 64); o[h].x += __shfl_xor(o[h].x, 32, 64);
      o[h].y += __shfl_xor(o[h].y, 16, 64); o[h].y += __shfl_xor(o[h].y, 32, 64);
      o[h].z += __shfl_xor(o[h].z, 16, 64); o[h].z += __shfl_xor(o[h].z, 32, 64);
      o[h].w += __shfl_xor(o[h].w, 16, 64); o[h].w += __shfl_xor(o[h].w, 32, 64);
    }
    // ---- cross-wave combine ----
    __syncthreads();                           // all waves done reading probs
    float* opart = &sc[0][0];                  // [wave][head][64d] = 16 KB
    if (js == 0) {
#pragma unroll
      for (int h = 0; h < NH; ++h)
        *(float4*)(opart + (((w << 3) + h) << 6) + 4 * dq) = o[h];
    }
    __syncthreads();
    float r = 0.f;                             // wave w reduces head w, lane=d
#pragma unroll
    for (int wv = 0; wv < 8; ++wv) r += opart[(((wv << 3) + w) << 6) + lane];
    out[(((size_t)b * NH + w) * L + i) * D + lane] = r;
  }
}

// ---------------------------------------------------------------------------
// K3: out[b,h,i,d] += sum_j attn[b,h,i,j] * v[b,h,j,d]   (tiled GEMM)
// grid (16, 16): i-tile 32, d=64, j staged 64 at a time. v gets full LDS
// reuse here. Runs after k2 on same stream (reads out, adds, stores).
// ---------------------------------------------------------------------------
__global__ __launch_bounds__(256) void k3_av(const float* __restrict__ attn,
                                             const float* __restrict__ v,
                                             float* __restrict__ out) {
  const int bh = blockIdx.x, it = blockIdx.y;
  __shared__ float As[32][68];    // attn tile [i][j], b128-aligned reads
  __shared__ float Vt[64][65];    // v tile transposed [d][j], stride 65
  const int t = threadIdx.x;
  const float* ab = attn + ((size_t)bh * L + it * 32) * L;
  const float* vb = v + (size_t)bh * (size_t)(L * D);
  const int i0 = t >> 4, j0 = t & 15;         // i = i0+16m (m<2), d = j0+16n
  float acc[2][4] = {};
#pragma unroll 1
  for (int jc = 0; jc < L; jc += 64) {
    __syncthreads();
#pragma unroll
    for (int n0 = 0; n0 < 2; ++n0) {          // attn: 32x64 = 512 f4
      int n = t + (n0 << 8);
      int r = n >> 4, c = (n & 15) << 2;
      *(float4*)&As[r][c] = *(const float4*)(ab + (size_t)r * L + jc + c);
    }
#pragma unroll
    for (int n0 = 0; n0 < 4; ++n0) {          // v: 64x64 = 1024 f4, transpose
      int n = t + (n0 << 8);
      int r = n >> 4, c = (n & 15) << 2;
      float4 a = *(const float4*)(vb + (size_t)(jc + r) * D + c);
      Vt[c][r] = a.x; Vt[c + 1][r] = a.y; Vt[c + 2][r] = a.z; Vt[c + 3][r] = a.w;
    }
    __syncthreads();
#pragma unroll 1
    for (int kc = 0; kc < 64; kc += 4) {
      float4 a[2];
#pragma unroll
      for (int m = 0; m < 2; ++m) a[m] = *(const float4*)&As[i0 + 16 * m][kc];
      float bb[4][4];
#pragma unroll
      for (int n = 0; n < 4; ++n) {
        const float* vr = &Vt[j0 + 16 * n][kc];
        bb[n][0] = vr[0]; bb[n][1] = vr[1]; bb[n][2] = vr[2]; bb[n][3] = vr[3];
      }
#pragma unroll
      for (int m = 0; m < 2; ++m)
#pragma unroll
        for (int n = 0; n < 4; ++n)
          acc[m][n] = fmaf(a[m].x, bb[n][0],
                      fmaf(a[m].y, bb[n][1],
                      fmaf(a[m].z, bb[n][2],
                      fmaf(a[m].w, bb[n][3], acc[m][n]))));
    }
  }
  float* ob = out + ((size_t)bh * L + it * 32) * D;
#pragma unroll
  for (int m = 0; m < 2; ++m)
#pragma unroll
    for (int n = 0; n < 4; ++n) {
      float* p = ob + (size_t)(i0 + 16 * m) * D + j0 + 16 * n;
      *p += acc[m][n];                        // RMW; k2 ran first (same stream)
    }
}

// ---------------------------------------------------------------------------
extern "C" void kernel_launch(void* const* d_in, const int* in_sizes, int n_in,
                              void* d_out, int out_size, void* d_ws, size_t ws_size,
                              hipStream_t stream) {
  const float* q     = (const float*)d_in[0];
  const float* k     = (const float*)d_in[1];
  const float* v     = (const float*)d_in[2];
  const float* adj_k = (const float*)d_in[3];
  const float* adj_v = (const float*)d_in[4];
  const int*   mask  = (const int*)d_in[5];
  float* out  = (float*)d_out;
  float* attn = out + (size_t)B * NH * L * D;   // second output region
  float* s1   = (float*)d_ws;                   // B*NH*L*L fp32 = 16.8 MB

  dim3 g1(B * NH, L / 64, L / 64);
  k1_qk<<<g1, 256, 0, stream>>>(q, k, s1);
  k2_fused<<<B * L, 512, 0, stream>>>(q, adj_k, adj_v, mask, s1, out, attn);
  dim3 g3(B * NH, L / 32);
  k3_av<<<g3, 256, 0, stream>>>(attn, v, out);
}